// Round 3
// baseline (12372.058 us; speedup 1.0000x reference)
//
#include <hip/hip_runtime.h>
#include <hip/hip_bf16.h>
#include <hip/hip_cooperative_groups.h>
#include <math.h>

namespace cg = cooperative_groups;

typedef unsigned short u16;
typedef __attribute__((ext_vector_type(8))) short short8;
typedef __attribute__((ext_vector_type(4))) float f32x4;

static __device__ __forceinline__ u16 f2b(float x) {
  __hip_bfloat16 h = __float2bfloat16(x);
  return *reinterpret_cast<u16*>(&h);
}
static __device__ __forceinline__ float b2f(u16 u) {
  unsigned int v = ((unsigned int)u) << 16;
  float f;
  __builtin_memcpy(&f, &v, 4);
  return f;
}

// ---------------- conversion kernels ----------------

__global__ void cvt_flat(const float* __restrict__ s, u16* __restrict__ d, long n) {
  long i = ((long)blockIdx.x * 256 + threadIdx.x) * 4;
  long stride = (long)gridDim.x * 1024;
  for (; i < n; i += stride) {
    float4 v = *(const float4*)(s + i);
    ushort4 o;
    o.x = f2b(v.x); o.y = f2b(v.y); o.z = f2b(v.z); o.w = f2b(v.w);
    *(ushort4*)(d + i) = o;
  }
}

__global__ void cvt_strided(const float* __restrict__ s, u16* __restrict__ d,
                            long total, int lshift, long sstride, long soff) {
  long i = (long)blockIdx.x * 256 + threadIdx.x;
  long step = (long)gridDim.x * 256;
  long mask = (1L << lshift) - 1;
  for (; i < total; i += step) {
    long r = i >> lshift;
    long c = i & mask;
    d[i] = f2b(s[r * sstride + soff + c]);
  }
}

__global__ void cvt_x(const float* __restrict__ gt, u16* __restrict__ d) {
  long idx = (long)blockIdx.x * 256 + threadIdx.x;
  if (idx >= 1024L * 512) return;
  long m = idx >> 9;
  int k = (int)(idx & 511);
  if (m < 992) {
    int tt = (int)(m >> 5), b = (int)(m & 31);
    d[idx] = f2b(gt[((long)b * 32 + tt) * 512 + k]);
  } else {
    d[idx] = 0;
  }
}

// ---------------- generic MFMA GEMM: C = A(M,K) * B(N,K)^T ----------------
// 128x128 tile, BK=32, 4 waves. Block->tile ordering groups 8 col-tiles x all
// row-tiles so the concurrent window shares one B col-panel (L3 reuse).
template<int EPI>
__global__ __launch_bounds__(256)
void gemm_bt(const u16* __restrict__ A, const u16* __restrict__ B,
             void* __restrict__ C0,
             const float* __restrict__ bias, const float* __restrict__ pw,
             int M, int N, int K) {
  __shared__ u16 As[4096];
  __shared__ u16 Bs[4096];
  const int tid = threadIdx.x;
  const int lane = tid & 63, wid = tid >> 6;

  int gx = gridDim.x, gy = gridDim.y;
  int orig = blockIdx.y * gx + blockIdx.x;
  int G = gx < 8 ? gx : 8;
  int ng = gx / G;
  int full = ng * G * gy;
  int ct, rt;
  if (orig < full) {
    int grp = orig / (G * gy), rem = orig % (G * gy);
    ct = grp * G + rem % G;
    rt = rem / G;
  } else {
    int Gt = gx - ng * G;
    int rem = orig - full;
    ct = ng * G + rem % Gt;
    rt = rem / Gt;
  }
  const long row0 = (long)rt * 128;
  const long col0 = (long)ct * 128;

  const int wm = (wid >> 1) * 64, wn = (wid & 1) * 64;
  const int fr = lane & 15, fq = lane >> 4;
  const int sr = wid * 16 + (lane >> 2);
  const int sc = (lane & 3) * 8;

  const u16* Ag0 = A + (row0 + sr) * (long)K + sc;
  const u16* Ag1 = Ag0 + 64 * (long)K;
  const u16* Bg0 = B + (col0 + sr) * (long)K + sc;
  const u16* Bg1 = Bg0 + 64 * (long)K;

  u16* AsW0 = &As[wid * 512];
  u16* AsW1 = &As[2048 + wid * 512];
  u16* BsW0 = &Bs[wid * 512];
  u16* BsW1 = &Bs[2048 + wid * 512];

  f32x4 acc[4][4];
#pragma unroll
  for (int i = 0; i < 4; ++i)
#pragma unroll
    for (int j = 0; j < 4; ++j) acc[i][j] = {0.f, 0.f, 0.f, 0.f};

  for (int k0 = 0; k0 < K; k0 += 32) {
    __builtin_amdgcn_global_load_lds((const __attribute__((address_space(1))) void*)(Ag0 + k0),
                                     (__attribute__((address_space(3))) void*)AsW0, 16, 0, 0);
    __builtin_amdgcn_global_load_lds((const __attribute__((address_space(1))) void*)(Ag1 + k0),
                                     (__attribute__((address_space(3))) void*)AsW1, 16, 0, 0);
    __builtin_amdgcn_global_load_lds((const __attribute__((address_space(1))) void*)(Bg0 + k0),
                                     (__attribute__((address_space(3))) void*)BsW0, 16, 0, 0);
    __builtin_amdgcn_global_load_lds((const __attribute__((address_space(1))) void*)(Bg1 + k0),
                                     (__attribute__((address_space(3))) void*)BsW1, 16, 0, 0);
    __syncthreads();
    short8 af[4], bfv[4];
#pragma unroll
    for (int i = 0; i < 4; ++i) af[i] = *(const short8*)&As[(wm + i * 16 + fr) * 32 + fq * 8];
#pragma unroll
    for (int i = 0; i < 4; ++i) bfv[i] = *(const short8*)&Bs[(wn + i * 16 + fr) * 32 + fq * 8];
#pragma unroll
    for (int i = 0; i < 4; ++i)
#pragma unroll
      for (int j = 0; j < 4; ++j)
        acc[i][j] = __builtin_amdgcn_mfma_f32_16x16x32_bf16(af[i], bfv[j], acc[i][j], 0, 0, 0);
    __syncthreads();
  }

#pragma unroll
  for (int i = 0; i < 4; ++i)
#pragma unroll
    for (int j = 0; j < 4; ++j)
#pragma unroll
      for (int q = 0; q < 4; ++q) {
        long gr = row0 + wm + i * 16 + fq * 4 + q;
        long gc = col0 + wn + j * 16 + fr;
        float v = acc[i][j][q];
        if constexpr (EPI == 0) {
          ((u16*)C0)[gr * (long)N + gc] = f2b(v);
        } else if constexpr (EPI == 1) {
          ((float*)C0)[gr * (long)N + gc] = tanhf(v + bias[gc]) * pw[gc];
        } else if constexpr (EPI == 2) {
          if (gr < M) ((float*)C0)[gr * (long)N + gc] = v + bias[gc];
        } else {  // EPI == 3
          if (gr < M) {
            long bb = gr & 31, tt = gr >> 5;
            float o = v + bias[gc];
            __builtin_nontemporal_store(o, &((float*)C0)[(bb * 31 + tt) * (long)N + gc]);
          }
        }
      }
}

// ---------------- persistent cooperative recurrence kernel ----------------
// 256 blocks x 512 threads. Per step:
//   phase A (gates): block owns 13 rows of Wcat; tid -> (b = tid>>4, kc = tid&15)
//   grid.sync()
//   phase B (attn+GRU): block = (b = blk>>3, jc = blk&7); 512 threads
//   grid.sync()
__global__ __launch_bounds__(512)
void recurrence(const u16* __restrict__ Wcat, const float* __restrict__ bcat,
                const float* __restrict__ wvf, const u16* __restrict__ FWb,
                const float* __restrict__ GX, const float* __restrict__ pb,
                float* __restrict__ h, u16* __restrict__ hbf,
                float* __restrict__ uh, float* __restrict__ gh,
                u16* __restrict__ Hbuf) {
  cg::grid_group grid = cg::this_grid();
  const int tid = threadIdx.x;
  const int blk = blockIdx.x;

  __shared__ float uhl[256];
  __shared__ float part[512];
  __shared__ float attn[128];
  __shared__ float gmp[3][512];

  const int gb = tid >> 4;   // phase A: batch row
  const int kc = tid & 15;   // phase A: k-chunk of 64
  const int r0 = blk * 13;
  const int bb = blk >> 3;   // phase B: batch row
  const int jc = blk & 7;    // phase B: column chunk

  for (int t = 0; t < 31; ++t) {
    // ---------------- phase A: uh + gh gates GEMV ----------------
    {
      float hf[64];
      const u16* hp = hbf + gb * 1024 + kc * 64;
#pragma unroll
      for (int j = 0; j < 8; ++j) {
        short8 hv = *(const short8*)(hp + j * 8);
#pragma unroll
        for (int e = 0; e < 8; ++e) hf[j * 8 + e] = b2f((u16)hv[e]);
      }
#pragma unroll
      for (int rr = 0; rr < 13; ++rr) {
        int r = r0 + rr;
        const u16* wr = Wcat + (long)r * 1024 + kc * 64;
        float p = 0.f;
#pragma unroll
        for (int j = 0; j < 8; ++j) {
          short8 wv = *(const short8*)(wr + j * 8);
#pragma unroll
          for (int e = 0; e < 8; ++e) p += b2f((u16)wv[e]) * hf[j * 8 + e];
        }
        p += __shfl_xor(p, 1);
        p += __shfl_xor(p, 2);
        p += __shfl_xor(p, 4);
        p += __shfl_xor(p, 8);
        if (kc == 0) {
          float val = p + bcat[r];
          if (r < 256) uh[gb * 256 + r] = tanhf(val);
          else gh[(long)gb * 3072 + (r - 256)] = val;
        }
      }
    }
    grid.sync();

    // ---------------- phase B: attention + gm + GRU ----------------
    {
      if (tid < 256) uhl[tid] = uh[bb * 256 + tid];
      __syncthreads();
      // scores: s = tid&127, q4 = tid>>7 covers 64 of the 256 dims
      {
        const int s = tid & 127, q4 = tid >> 7;
        const float* wr = wvf + ((long)(bb * 128 + s)) * 256 + q4 * 64;
        const float* u = &uhl[q4 * 64];
        float p = 0.f;
#pragma unroll
        for (int d = 0; d < 64; d += 4) {
          float4 wv = *(const float4*)(wr + d);
          p += u[d] * wv.x + u[d + 1] * wv.y + u[d + 2] * wv.z + u[d + 3] * wv.w;
        }
        part[tid] = p;
      }
      __syncthreads();
      if (tid < 128)
        attn[tid] = part[tid] + part[tid + 128] + part[tid + 256] + part[tid + 384] + pb[0];
      __syncthreads();
      if (tid < 64) {
        float m = fmaxf(attn[tid], attn[tid + 64]);
#pragma unroll
        for (int o = 32; o; o >>= 1) m = fmaxf(m, __shfl_xor(m, o));
        float e0 = expf(attn[tid] - m), e1 = expf(attn[tid + 64] - m);
        float s2 = e0 + e1;
#pragma unroll
        for (int o = 32; o; o >>= 1) s2 += __shfl_xor(s2, o);
        float inv = 1.f / s2;
        attn[tid] = e0 * inv;
        attn[tid + 64] = e1 * inv;
      }
      __syncthreads();
      // gm: ml = tid&127 -> col, sh = tid>>7 -> 32 attention positions each
      {
        const int ml = tid & 127, sh = tid >> 7;
        const int col = jc * 128 + ml;
        float g0 = 0.f, g1 = 0.f, g2 = 0.f;
        const u16* fw = FWb + ((long)(bb * 128 + sh * 32)) * 3072 + col;
#pragma unroll 4
        for (int s = 0; s < 32; ++s) {
          float a = attn[sh * 32 + s];
          g0 += a * b2f(fw[0]);
          g1 += a * b2f(fw[1024]);
          g2 += a * b2f(fw[2048]);
          fw += 3072;
        }
        gmp[0][tid] = g0; gmp[1][tid] = g1; gmp[2][tid] = g2;
      }
      __syncthreads();
      if (tid < 128) {
        float gr_ = gmp[0][tid] + gmp[0][tid + 128] + gmp[0][tid + 256] + gmp[0][tid + 384];
        float gz_ = gmp[1][tid] + gmp[1][tid + 128] + gmp[1][tid + 256] + gmp[1][tid + 384];
        float gn_ = gmp[2][tid] + gmp[2][tid + 128] + gmp[2][tid + 256] + gmp[2][tid + 384];
        const int m = jc * 128 + tid;
        const long gxo = ((long)t * 32 + bb) * 3072;
        float xr = GX[gxo + m] + gr_;
        float xz = GX[gxo + 1024 + m] + gz_;
        float xn = GX[gxo + 2048 + m] + gn_;
        float hr = gh[(long)bb * 3072 + m];
        float hz = gh[(long)bb * 3072 + 1024 + m];
        float hn = gh[(long)bb * 3072 + 2048 + m];
        float r = 1.f / (1.f + expf(-(xr + hr)));
        float z = 1.f / (1.f + expf(-(xz + hz)));
        float n = tanhf(xn + r * hn);
        float hv = h[(long)bb * 1024 + m];
        float h2 = (1.f - z) * n + z * hv;
        h[(long)bb * 1024 + m] = h2;
        u16 hb_ = f2b(h2);
        hbf[bb * 1024 + m] = hb_;
        Hbuf[((long)t * 32 + bb) * 1024 + m] = hb_;
      }
    }
    grid.sync();
  }
}

// ---------------- launcher ----------------

extern "C" void kernel_launch(void* const* d_in, const int* in_sizes, int n_in,
                              void* d_out, int out_size, void* d_ws, size_t ws_size,
                              hipStream_t stream) {
  const float* f    = (const float*)d_in[0];
  const float* h0   = (const float*)d_in[1];
  const float* gt   = (const float*)d_in[2];
  const float* U_w  = (const float*)d_in[4];
  const float* U_b  = (const float*)d_in[5];
  const float* V_w  = (const float*)d_in[6];
  const float* V_b  = (const float*)d_in[7];
  const float* P_w  = (const float*)d_in[8];
  const float* P_b  = (const float*)d_in[9];
  const float* W_ih = (const float*)d_in[10];
  const float* b_ih = (const float*)d_in[11];
  const float* W_hh = (const float*)d_in[12];
  const float* b_hh = (const float*)d_in[13];
  const float* dw   = (const float*)d_in[14];
  const float* db   = (const float*)d_in[15];

  char* w = (char*)d_ws;
  auto alloc = [&](size_t bytes) { char* p = w; w += (bytes + 255) & ~255ULL; return p; };

  u16*   fbf   = (u16*)alloc(4096L * 1024 * 2);
  u16*   VwBf  = (u16*)alloc(256L * 1024 * 2);
  u16*   Wcat  = (u16*)alloc(3328L * 1024 * 2);
  u16*   WxBf  = (u16*)alloc(3072L * 512 * 2);
  u16*   WmBf  = (u16*)alloc(3072L * 1024 * 2);
  u16*   dwBf  = (u16*)alloc(32000L * 1024 * 2);
  u16*   Xbf   = (u16*)alloc(1024L * 512 * 2);
  float* wvf   = (float*)alloc(4096L * 256 * 4);
  float* GX    = (float*)alloc(1024L * 3072 * 4);
  u16*   FWb   = (u16*)alloc(4096L * 3072 * 2);
  float* hf32  = (float*)alloc(32L * 1024 * 4);
  u16*   hbf   = (u16*)alloc(128L * 1024 * 2);
  float* uh    = (float*)alloc(32L * 256 * 4);
  float* ghb   = (float*)alloc(32L * 3072 * 4);
  u16*   Hbuf  = (u16*)alloc(1024L * 1024 * 2);
  float* bcat  = (float*)alloc(3328L * 4);

  auto cvg = [](long n) { long g = (n + 1023) / 1024; return (int)(g > 2048 ? 2048 : g); };

  cvt_flat<<<cvg(4194304), 256, 0, stream>>>(f, fbf, 4194304);
  cvt_flat<<<cvg(262144), 256, 0, stream>>>(V_w, VwBf, 262144);
  cvt_flat<<<cvg(262144), 256, 0, stream>>>(U_w, Wcat, 262144);
  cvt_flat<<<cvg(3145728), 256, 0, stream>>>(W_hh, Wcat + 262144L, 3145728);
  cvt_strided<<<2048, 256, 0, stream>>>(W_ih, WxBf, 3072L * 512, 9, 1536, 0);
  cvt_strided<<<2048, 256, 0, stream>>>(W_ih, WmBf, 3072L * 1024, 10, 1536, 512);
  cvt_flat<<<cvg(32768000), 256, 0, stream>>>(dw, dwBf, 32768000);
  cvt_x<<<2048, 256, 0, stream>>>(gt, Xbf);
  cvt_flat<<<cvg(32768), 256, 0, stream>>>(h0, hbf, 32768);
  hipMemcpyAsync(hf32, h0, 32L * 1024 * 4, hipMemcpyDeviceToDevice, stream);
  hipMemcpyAsync(bcat, U_b, 256 * 4, hipMemcpyDeviceToDevice, stream);
  hipMemcpyAsync(bcat + 256, b_hh, 3072 * 4, hipMemcpyDeviceToDevice, stream);

  // loop-invariant GEMMs
  gemm_bt<1><<<dim3(2, 32), 256, 0, stream>>>(fbf, VwBf, wvf, V_b, P_w, 4096, 256, 1024);
  gemm_bt<2><<<dim3(24, 8), 256, 0, stream>>>(Xbf, WxBf, GX, b_ih, nullptr, 992, 3072, 512);
  gemm_bt<0><<<dim3(24, 32), 256, 0, stream>>>(fbf, WmBf, FWb, nullptr, nullptr, 4096, 3072, 1024);

  // full recurrence: one persistent cooperative kernel
  {
    void* ka[] = {(void*)&Wcat, (void*)&bcat, (void*)&wvf, (void*)&FWb,
                  (void*)&GX,   (void*)&P_b,  (void*)&hf32, (void*)&hbf,
                  (void*)&uh,   (void*)&ghb,  (void*)&Hbuf};
    hipLaunchCooperativeKernel((void*)recurrence, dim3(256), dim3(512), ka, 0, stream);
  }

  // logits
  gemm_bt<3><<<dim3(250, 8), 256, 0, stream>>>(Hbuf, dwBf, (float*)d_out, db, nullptr,
                                               992, 32000, 1024);
}

// Round 4
// 3436.491 us; speedup vs baseline: 3.6002x; 3.6002x over previous
//
#include <hip/hip_runtime.h>
#include <hip/hip_bf16.h>
#include <math.h>

typedef unsigned short u16;
typedef __attribute__((ext_vector_type(8))) short short8;
typedef __attribute__((ext_vector_type(4))) float f32x4;

static __device__ __forceinline__ u16 f2b(float x) {
  __hip_bfloat16 h = __float2bfloat16(x);
  return *reinterpret_cast<u16*>(&h);
}
static __device__ __forceinline__ float b2f(u16 u) {
  unsigned int v = ((unsigned int)u) << 16;
  float f;
  __builtin_memcpy(&f, &v, 4);
  return f;
}

// ---------------- conversion kernels ----------------

__global__ void cvt_flat(const float* __restrict__ s, u16* __restrict__ d, long n) {
  long i = ((long)blockIdx.x * 256 + threadIdx.x) * 4;
  long stride = (long)gridDim.x * 1024;
  for (; i < n; i += stride) {
    float4 v = *(const float4*)(s + i);
    ushort4 o;
    o.x = f2b(v.x); o.y = f2b(v.y); o.z = f2b(v.z); o.w = f2b(v.w);
    *(ushort4*)(d + i) = o;
  }
}

__global__ void cvt_strided(const float* __restrict__ s, u16* __restrict__ d,
                            long total, int lshift, long sstride, long soff) {
  long i = (long)blockIdx.x * 256 + threadIdx.x;
  long step = (long)gridDim.x * 256;
  long mask = (1L << lshift) - 1;
  for (; i < total; i += step) {
    long r = i >> lshift;
    long c = i & mask;
    d[i] = f2b(s[r * sstride + soff + c]);
  }
}

__global__ void cvt_x(const float* __restrict__ gt, u16* __restrict__ d) {
  long idx = (long)blockIdx.x * 256 + threadIdx.x;
  if (idx >= 1024L * 512) return;
  long m = idx >> 9;
  int k = (int)(idx & 511);
  if (m < 992) {
    int tt = (int)(m >> 5), b = (int)(m & 31);
    d[idx] = f2b(gt[((long)b * 32 + tt) * 512 + k]);
  } else {
    d[idx] = 0;
  }
}

// ---------------- generic MFMA GEMM: C = A(M,K) * B(N,K)^T ----------------
// 128x128 tile, BK=32, 4 waves. Block->tile ordering groups 8 col-tiles x all
// row-tiles so the concurrent window shares one B col-panel (L3 reuse).
template<int EPI>
__global__ __launch_bounds__(256)
void gemm_bt(const u16* __restrict__ A, const u16* __restrict__ B,
             void* __restrict__ C0,
             const float* __restrict__ bias, const float* __restrict__ pw,
             int M, int N, int K) {
  __shared__ u16 As[4096];
  __shared__ u16 Bs[4096];
  const int tid = threadIdx.x;
  const int lane = tid & 63, wid = tid >> 6;

  int gx = gridDim.x, gy = gridDim.y;
  int orig = blockIdx.y * gx + blockIdx.x;
  int G = gx < 8 ? gx : 8;
  int ng = gx / G;
  int full = ng * G * gy;
  int ct, rt;
  if (orig < full) {
    int grp = orig / (G * gy), rem = orig % (G * gy);
    ct = grp * G + rem % G;
    rt = rem / G;
  } else {
    int Gt = gx - ng * G;
    int rem = orig - full;
    ct = ng * G + rem % Gt;
    rt = rem / Gt;
  }
  const long row0 = (long)rt * 128;
  const long col0 = (long)ct * 128;

  const int wm = (wid >> 1) * 64, wn = (wid & 1) * 64;
  const int fr = lane & 15, fq = lane >> 4;
  const int sr = wid * 16 + (lane >> 2);
  const int sc = (lane & 3) * 8;

  const u16* Ag0 = A + (row0 + sr) * (long)K + sc;
  const u16* Ag1 = Ag0 + 64 * (long)K;
  const u16* Bg0 = B + (col0 + sr) * (long)K + sc;
  const u16* Bg1 = Bg0 + 64 * (long)K;

  u16* AsW0 = &As[wid * 512];
  u16* AsW1 = &As[2048 + wid * 512];
  u16* BsW0 = &Bs[wid * 512];
  u16* BsW1 = &Bs[2048 + wid * 512];

  f32x4 acc[4][4];
#pragma unroll
  for (int i = 0; i < 4; ++i)
#pragma unroll
    for (int j = 0; j < 4; ++j) acc[i][j] = {0.f, 0.f, 0.f, 0.f};

  for (int k0 = 0; k0 < K; k0 += 32) {
    __builtin_amdgcn_global_load_lds((const __attribute__((address_space(1))) void*)(Ag0 + k0),
                                     (__attribute__((address_space(3))) void*)AsW0, 16, 0, 0);
    __builtin_amdgcn_global_load_lds((const __attribute__((address_space(1))) void*)(Ag1 + k0),
                                     (__attribute__((address_space(3))) void*)AsW1, 16, 0, 0);
    __builtin_amdgcn_global_load_lds((const __attribute__((address_space(1))) void*)(Bg0 + k0),
                                     (__attribute__((address_space(3))) void*)BsW0, 16, 0, 0);
    __builtin_amdgcn_global_load_lds((const __attribute__((address_space(1))) void*)(Bg1 + k0),
                                     (__attribute__((address_space(3))) void*)BsW1, 16, 0, 0);
    __syncthreads();
    short8 af[4], bfv[4];
#pragma unroll
    for (int i = 0; i < 4; ++i) af[i] = *(const short8*)&As[(wm + i * 16 + fr) * 32 + fq * 8];
#pragma unroll
    for (int i = 0; i < 4; ++i) bfv[i] = *(const short8*)&Bs[(wn + i * 16 + fr) * 32 + fq * 8];
#pragma unroll
    for (int i = 0; i < 4; ++i)
#pragma unroll
      for (int j = 0; j < 4; ++j)
        acc[i][j] = __builtin_amdgcn_mfma_f32_16x16x32_bf16(af[i], bfv[j], acc[i][j], 0, 0, 0);
    __syncthreads();
  }

#pragma unroll
  for (int i = 0; i < 4; ++i)
#pragma unroll
    for (int j = 0; j < 4; ++j)
#pragma unroll
      for (int q = 0; q < 4; ++q) {
        long gr = row0 + wm + i * 16 + fq * 4 + q;
        long gc = col0 + wn + j * 16 + fr;
        float v = acc[i][j][q];
        if constexpr (EPI == 0) {
          ((u16*)C0)[gr * (long)N + gc] = f2b(v);
        } else if constexpr (EPI == 1) {
          ((float*)C0)[gr * (long)N + gc] = tanhf(v + bias[gc]) * pw[gc];
        } else if constexpr (EPI == 2) {
          if (gr < M) ((float*)C0)[gr * (long)N + gc] = v + bias[gc];
        } else {  // EPI == 3
          if (gr < M) {
            long bb = gr & 31, tt = gr >> 5;
            float o = v + bias[gc];
            __builtin_nontemporal_store(o, &((float*)C0)[(bb * 31 + tt) * (long)N + gc]);
          }
        }
      }
}

// ---------------- fully fused per-step kernel ----------------
// grid 256 = (b = blk>>3, jc = blk&7), 512 threads. All deps intra-block:
//   A: h[b,:] -> LDS
//   B: uh[0:256] (redundant per jc; f32 weights)
//   C: scores + softmax
//   D: gm partials (jc col-slice of FWb, bf16)
//   E: gh partials (jc row-slice of W_hh, f32)
//   F: GRU combine, write h + Hbuf slice
// jc = blk&7 => all blocks with a given jc land on one XCD (RR dispatch), so
// that XCD's W_hh row-slice (1.5 MB) + FWb col-slice (3.1 MB) stay L2-resident.
__global__ __launch_bounds__(512)
void stepk(const float* __restrict__ Wcat,  // (3328,1024) f32: [U_w; W_hh]
           const float* __restrict__ bcat,  // (3328,) f32: [U_b; b_hh]
           const float* __restrict__ wvf,   // (4096,256) f32
           const u16* __restrict__ FWb,     // (4096,3072) bf16
           const float* __restrict__ GX,    // (1024,3072) f32, row t*32+b
           const float* __restrict__ pb,    // P_b
           float* __restrict__ h,           // (32,1024) f32
           u16* __restrict__ Hbuf,          // (1024,1024) bf16, row t*32+b
           int t) {
  const int blk = blockIdx.x;
  const int b = blk >> 3, jc = blk & 7;
  const int tid = threadIdx.x;

  __shared__ float hl[1024];
  __shared__ float uhl[256];
  __shared__ float part[512];
  __shared__ float attn[128];
  __shared__ float gmp[3][512];
  __shared__ float ghp[3][512];

  // A: load h into LDS
  {
    float2 v = *(const float2*)(h + b * 1024 + tid * 2);
    hl[tid * 2] = v.x;
    hl[tid * 2 + 1] = v.y;
  }
  __syncthreads();

  // B: uh (redundant per jc). d = tid>>1, half = tid&1 covers 512 k's.
  {
    const int d = tid >> 1, half = tid & 1;
    const float* wr = Wcat + (long)d * 1024 + half * 512;
    const float* hh = &hl[half * 512];
    float p = 0.f;
#pragma unroll 8
    for (int k = 0; k < 512; k += 4) {
      float4 wv = *(const float4*)(wr + k);
      float4 hv = *(const float4*)(hh + k);
      p += wv.x * hv.x + wv.y * hv.y + wv.z * hv.z + wv.w * hv.w;
    }
    p += __shfl_xor(p, 1);
    if (half == 0) uhl[d] = tanhf(p + bcat[d]);
  }
  __syncthreads();

  // C: scores + softmax. s = tid&127, q = tid>>7 covers 64 of 256 dims.
  {
    const int s = tid & 127, q = tid >> 7;
    const float* wr = wvf + ((long)(b * 128 + s)) * 256 + q * 64;
    const float* u = &uhl[q * 64];
    float p = 0.f;
#pragma unroll
    for (int d = 0; d < 64; d += 4) {
      float4 wv = *(const float4*)(wr + d);
      float4 uv = *(const float4*)(u + d);
      p += wv.x * uv.x + wv.y * uv.y + wv.z * uv.z + wv.w * uv.w;
    }
    part[tid] = p;
  }
  __syncthreads();
  if (tid < 128)
    attn[tid] = part[tid] + part[tid + 128] + part[tid + 256] + part[tid + 384] + pb[0];
  __syncthreads();
  if (tid < 64) {
    float m = fmaxf(attn[tid], attn[tid + 64]);
#pragma unroll
    for (int o = 32; o; o >>= 1) m = fmaxf(m, __shfl_xor(m, o));
    float e0 = expf(attn[tid] - m), e1 = expf(attn[tid + 64] - m);
    float s2 = e0 + e1;
#pragma unroll
    for (int o = 32; o; o >>= 1) s2 += __shfl_xor(s2, o);
    float inv = 1.f / s2;
    attn[tid] = e0 * inv;
    attn[tid + 64] = e1 * inv;
  }
  __syncthreads();

  const int ml = tid & 127, sh = tid >> 7;

  // D: gm partials. col = jc*128+ml; sh covers 32 attention positions.
  {
    const int col = jc * 128 + ml;
    float g0 = 0.f, g1 = 0.f, g2 = 0.f;
    const u16* fw = FWb + ((long)(b * 128 + sh * 32)) * 3072 + col;
#pragma unroll 4
    for (int s = 0; s < 32; ++s) {
      float a = attn[sh * 32 + s];
      g0 += a * b2f(fw[0]);
      g1 += a * b2f(fw[1024]);
      g2 += a * b2f(fw[2048]);
      fw += 3072;
    }
    gmp[0][tid] = g0; gmp[1][tid] = g1; gmp[2][tid] = g2;
  }

  // E: gh partials. rows {m, 1024+m, 2048+m} of W_hh; sh covers k-quarter.
  {
    const int m = jc * 128 + ml;
    const float* hq = &hl[sh * 256];
    const float* w0 = Wcat + (long)(256 + m) * 1024 + sh * 256;
    const float* w1 = Wcat + (long)(256 + 1024 + m) * 1024 + sh * 256;
    const float* w2 = Wcat + (long)(256 + 2048 + m) * 1024 + sh * 256;
    float a0 = 0.f, a1 = 0.f, a2 = 0.f;
#pragma unroll 4
    for (int k = 0; k < 256; k += 4) {
      float4 hv = *(const float4*)(hq + k);
      float4 v0 = *(const float4*)(w0 + k);
      float4 v1 = *(const float4*)(w1 + k);
      float4 v2 = *(const float4*)(w2 + k);
      a0 += v0.x * hv.x + v0.y * hv.y + v0.z * hv.z + v0.w * hv.w;
      a1 += v1.x * hv.x + v1.y * hv.y + v1.z * hv.z + v1.w * hv.w;
      a2 += v2.x * hv.x + v2.y * hv.y + v2.z * hv.z + v2.w * hv.w;
    }
    ghp[0][tid] = a0; ghp[1][tid] = a1; ghp[2][tid] = a2;
  }
  __syncthreads();

  // F: GRU combine for cols jc*128 .. jc*128+127
  if (tid < 128) {
    const int m = jc * 128 + tid;
    float gm0 = gmp[0][tid] + gmp[0][tid + 128] + gmp[0][tid + 256] + gmp[0][tid + 384];
    float gm1 = gmp[1][tid] + gmp[1][tid + 128] + gmp[1][tid + 256] + gmp[1][tid + 384];
    float gm2 = gmp[2][tid] + gmp[2][tid + 128] + gmp[2][tid + 256] + gmp[2][tid + 384];
    float gh0 = ghp[0][tid] + ghp[0][tid + 128] + ghp[0][tid + 256] + ghp[0][tid + 384];
    float gh1 = ghp[1][tid] + ghp[1][tid + 128] + ghp[1][tid + 256] + ghp[1][tid + 384];
    float gh2 = ghp[2][tid] + ghp[2][tid + 128] + ghp[2][tid + 256] + ghp[2][tid + 384];
    const long gxo = ((long)t * 32 + b) * 3072;
    float xr = GX[gxo + m] + gm0;
    float xz = GX[gxo + 1024 + m] + gm1;
    float xn = GX[gxo + 2048 + m] + gm2;
    float hr = gh0 + bcat[256 + m];
    float hz = gh1 + bcat[256 + 1024 + m];
    float hn = gh2 + bcat[256 + 2048 + m];
    float r = 1.f / (1.f + expf(-(xr + hr)));
    float z = 1.f / (1.f + expf(-(xz + hz)));
    float n = tanhf(xn + r * hn);
    float hv = hl[m];
    float h2 = (1.f - z) * n + z * hv;
    h[b * 1024 + m] = h2;
    Hbuf[((long)t * 32 + b) * 1024 + m] = f2b(h2);
  }
}

// ---------------- launcher ----------------

extern "C" void kernel_launch(void* const* d_in, const int* in_sizes, int n_in,
                              void* d_out, int out_size, void* d_ws, size_t ws_size,
                              hipStream_t stream) {
  const float* f    = (const float*)d_in[0];
  const float* h0   = (const float*)d_in[1];
  const float* gt   = (const float*)d_in[2];
  const float* U_w  = (const float*)d_in[4];
  const float* U_b  = (const float*)d_in[5];
  const float* V_w  = (const float*)d_in[6];
  const float* V_b  = (const float*)d_in[7];
  const float* P_w  = (const float*)d_in[8];
  const float* P_b  = (const float*)d_in[9];
  const float* W_ih = (const float*)d_in[10];
  const float* b_ih = (const float*)d_in[11];
  const float* W_hh = (const float*)d_in[12];
  const float* b_hh = (const float*)d_in[13];
  const float* dw   = (const float*)d_in[14];
  const float* db   = (const float*)d_in[15];

  char* w = (char*)d_ws;
  auto alloc = [&](size_t bytes) { char* p = w; w += (bytes + 255) & ~255ULL; return p; };

  u16*   fbf   = (u16*)alloc(4096L * 1024 * 2);
  u16*   VwBf  = (u16*)alloc(256L * 1024 * 2);
  float* Wcat  = (float*)alloc(3328L * 1024 * 4);  // f32 [U_w; W_hh]
  u16*   WxBf  = (u16*)alloc(3072L * 512 * 2);
  u16*   WmBf  = (u16*)alloc(3072L * 1024 * 2);
  u16*   dwBf  = (u16*)alloc(32000L * 1024 * 2);
  u16*   Xbf   = (u16*)alloc(1024L * 512 * 2);
  float* wvf   = (float*)alloc(4096L * 256 * 4);
  float* GX    = (float*)alloc(1024L * 3072 * 4);
  u16*   FWb   = (u16*)alloc(4096L * 3072 * 2);
  float* hf32  = (float*)alloc(32L * 1024 * 4);
  u16*   Hbuf  = (u16*)alloc(1024L * 1024 * 2);
  float* bcat  = (float*)alloc(3328L * 4);

  auto cvg = [](long n) { long g = (n + 1023) / 1024; return (int)(g > 2048 ? 2048 : g); };

  cvt_flat<<<cvg(4194304), 256, 0, stream>>>(f, fbf, 4194304);
  cvt_flat<<<cvg(262144), 256, 0, stream>>>(V_w, VwBf, 262144);
  cvt_strided<<<2048, 256, 0, stream>>>(W_ih, WxBf, 3072L * 512, 9, 1536, 0);
  cvt_strided<<<2048, 256, 0, stream>>>(W_ih, WmBf, 3072L * 1024, 10, 1536, 512);
  cvt_flat<<<cvg(32768000), 256, 0, stream>>>(dw, dwBf, 32768000);
  cvt_x<<<2048, 256, 0, stream>>>(gt, Xbf);
  hipMemcpyAsync(Wcat, U_w, 256L * 1024 * 4, hipMemcpyDeviceToDevice, stream);
  hipMemcpyAsync(Wcat + 262144, W_hh, 3072L * 1024 * 4, hipMemcpyDeviceToDevice, stream);
  hipMemcpyAsync(hf32, h0, 32L * 1024 * 4, hipMemcpyDeviceToDevice, stream);
  hipMemcpyAsync(bcat, U_b, 256 * 4, hipMemcpyDeviceToDevice, stream);
  hipMemcpyAsync(bcat + 256, b_hh, 3072 * 4, hipMemcpyDeviceToDevice, stream);

  // loop-invariant GEMMs
  gemm_bt<1><<<dim3(2, 32), 256, 0, stream>>>(fbf, VwBf, wvf, V_b, P_w, 4096, 256, 1024);
  gemm_bt<2><<<dim3(24, 8), 256, 0, stream>>>(Xbf, WxBf, GX, b_ih, nullptr, 992, 3072, 512);
  gemm_bt<0><<<dim3(24, 32), 256, 0, stream>>>(fbf, WmBf, FWb, nullptr, nullptr, 4096, 3072, 1024);

  // recurrence: ONE fused kernel per step
  for (int t = 0; t < 31; ++t) {
    stepk<<<256, 512, 0, stream>>>(Wcat, bcat, wvf, FWb, GX, P_b, hf32, Hbuf, t);
  }

  // logits
  gemm_bt<3><<<dim3(250, 8), 256, 0, stream>>>(Hbuf, dwBf, (float*)d_out, db, nullptr,
                                               992, 32000, 1024);
}

// Round 5
// 2206.038 us; speedup vs baseline: 5.6083x; 1.5578x over previous
//
#include <hip/hip_runtime.h>
#include <hip/hip_bf16.h>
#include <math.h>

typedef unsigned short u16;
typedef __attribute__((ext_vector_type(8))) short short8;
typedef __attribute__((ext_vector_type(4))) float f32x4;

static __device__ __forceinline__ u16 f2b(float x) {
  __hip_bfloat16 h = __float2bfloat16(x);
  return *reinterpret_cast<u16*>(&h);
}
static __device__ __forceinline__ float b2f(u16 u) {
  unsigned int v = ((unsigned int)u) << 16;
  float f;
  __builtin_memcpy(&f, &v, 4);
  return f;
}

// ---------------- conversion kernels ----------------

__global__ void cvt_flat(const float* __restrict__ s, u16* __restrict__ d, long n) {
  long i = ((long)blockIdx.x * 256 + threadIdx.x) * 4;
  long stride = (long)gridDim.x * 1024;
  for (; i < n; i += stride) {
    float4 v = *(const float4*)(s + i);
    ushort4 o;
    o.x = f2b(v.x); o.y = f2b(v.y); o.z = f2b(v.z); o.w = f2b(v.w);
    *(ushort4*)(d + i) = o;
  }
}

__global__ void cvt_strided(const float* __restrict__ s, u16* __restrict__ d,
                            long total, int lshift, long sstride, long soff) {
  long i = (long)blockIdx.x * 256 + threadIdx.x;
  long step = (long)gridDim.x * 256;
  long mask = (1L << lshift) - 1;
  for (; i < total; i += step) {
    long r = i >> lshift;
    long c = i & mask;
    d[i] = f2b(s[r * sstride + soff + c]);
  }
}

__global__ void cvt_x(const float* __restrict__ gt, u16* __restrict__ d) {
  long idx = (long)blockIdx.x * 256 + threadIdx.x;
  if (idx >= 1024L * 512) return;
  long m = idx >> 9;
  int k = (int)(idx & 511);
  if (m < 992) {
    int tt = (int)(m >> 5), b = (int)(m & 31);
    d[idx] = f2b(gt[((long)b * 32 + tt) * 512 + k]);
  } else {
    d[idx] = 0;
  }
}

// ---------------- generic MFMA GEMM: C = A(M,K) * B(N,K)^T ----------------
// 128x128 tile, BK=32, 4 waves. Block->tile ordering groups 8 col-tiles x all
// row-tiles so the concurrent window shares one B col-panel (L3 reuse).
// EPI: 0=bf16 out (FW), 1=bf16 out tanh(acc+bias)*pw (wvf),
//      2=f32 out acc+bias guard (GX), 3=f32 out remap row, +bias, NT (logits)
template<int EPI>
__global__ __launch_bounds__(256)
void gemm_bt(const u16* __restrict__ A, const u16* __restrict__ B,
             void* __restrict__ C0,
             const float* __restrict__ bias, const float* __restrict__ pw,
             int M, int N, int K) {
  __shared__ u16 As[4096];
  __shared__ u16 Bs[4096];
  const int tid = threadIdx.x;
  const int lane = tid & 63, wid = tid >> 6;

  int gx = gridDim.x, gy = gridDim.y;
  int orig = blockIdx.y * gx + blockIdx.x;
  int G = gx < 8 ? gx : 8;
  int ng = gx / G;
  int full = ng * G * gy;
  int ct, rt;
  if (orig < full) {
    int grp = orig / (G * gy), rem = orig % (G * gy);
    ct = grp * G + rem % G;
    rt = rem / G;
  } else {
    int Gt = gx - ng * G;
    int rem = orig - full;
    ct = ng * G + rem % Gt;
    rt = rem / Gt;
  }
  const long row0 = (long)rt * 128;
  const long col0 = (long)ct * 128;

  const int wm = (wid >> 1) * 64, wn = (wid & 1) * 64;
  const int fr = lane & 15, fq = lane >> 4;
  const int sr = wid * 16 + (lane >> 2);
  const int sc = (lane & 3) * 8;

  const u16* Ag0 = A + (row0 + sr) * (long)K + sc;
  const u16* Ag1 = Ag0 + 64 * (long)K;
  const u16* Bg0 = B + (col0 + sr) * (long)K + sc;
  const u16* Bg1 = Bg0 + 64 * (long)K;

  u16* AsW0 = &As[wid * 512];
  u16* AsW1 = &As[2048 + wid * 512];
  u16* BsW0 = &Bs[wid * 512];
  u16* BsW1 = &Bs[2048 + wid * 512];

  f32x4 acc[4][4];
#pragma unroll
  for (int i = 0; i < 4; ++i)
#pragma unroll
    for (int j = 0; j < 4; ++j) acc[i][j] = {0.f, 0.f, 0.f, 0.f};

  for (int k0 = 0; k0 < K; k0 += 32) {
    __builtin_amdgcn_global_load_lds((const __attribute__((address_space(1))) void*)(Ag0 + k0),
                                     (__attribute__((address_space(3))) void*)AsW0, 16, 0, 0);
    __builtin_amdgcn_global_load_lds((const __attribute__((address_space(1))) void*)(Ag1 + k0),
                                     (__attribute__((address_space(3))) void*)AsW1, 16, 0, 0);
    __builtin_amdgcn_global_load_lds((const __attribute__((address_space(1))) void*)(Bg0 + k0),
                                     (__attribute__((address_space(3))) void*)BsW0, 16, 0, 0);
    __builtin_amdgcn_global_load_lds((const __attribute__((address_space(1))) void*)(Bg1 + k0),
                                     (__attribute__((address_space(3))) void*)BsW1, 16, 0, 0);
    __syncthreads();
    short8 af[4], bfv[4];
#pragma unroll
    for (int i = 0; i < 4; ++i) af[i] = *(const short8*)&As[(wm + i * 16 + fr) * 32 + fq * 8];
#pragma unroll
    for (int i = 0; i < 4; ++i) bfv[i] = *(const short8*)&Bs[(wn + i * 16 + fr) * 32 + fq * 8];
#pragma unroll
    for (int i = 0; i < 4; ++i)
#pragma unroll
      for (int j = 0; j < 4; ++j)
        acc[i][j] = __builtin_amdgcn_mfma_f32_16x16x32_bf16(af[i], bfv[j], acc[i][j], 0, 0, 0);
    __syncthreads();
  }

#pragma unroll
  for (int i = 0; i < 4; ++i)
#pragma unroll
    for (int j = 0; j < 4; ++j)
#pragma unroll
      for (int q = 0; q < 4; ++q) {
        long gr = row0 + wm + i * 16 + fq * 4 + q;
        long gc = col0 + wn + j * 16 + fr;
        float v = acc[i][j][q];
        if constexpr (EPI == 0) {
          ((u16*)C0)[gr * (long)N + gc] = f2b(v);
        } else if constexpr (EPI == 1) {
          ((u16*)C0)[gr * (long)N + gc] = f2b(tanhf(v + bias[gc]) * pw[gc]);
        } else if constexpr (EPI == 2) {
          if (gr < M) ((float*)C0)[gr * (long)N + gc] = v + bias[gc];
        } else {  // EPI == 3
          if (gr < M) {
            long bb = gr & 31, tt = gr >> 5;
            float o = v + bias[gc];
            __builtin_nontemporal_store(o, &((float*)C0)[(bb * 31 + tt) * (long)N + gc]);
          }
        }
      }
}

// ---------------- partial-gates init (for t=0) ----------------
// grid 256 = (b = blk>>3, kc = blk&7). partial[b][kc][r] = Wcat[r, kc*128..+128) . h0[b, same]
__global__ __launch_bounds__(512)
void init_partial(const u16* __restrict__ Wcat, const float* __restrict__ h0,
                  float* __restrict__ pout) {
  const int b = blockIdx.x >> 3, kc = blockIdx.x & 7;
  const int tid = threadIdx.x;
  __shared__ float hl[128];
  if (tid < 128) hl[tid] = h0[b * 1024 + kc * 128 + tid];
  __syncthreads();
  for (int j = 0; j < 7; ++j) {
    int r = j * 512 + tid;
    if (r < 3328) {
      const u16* wr = Wcat + (long)r * 1024 + kc * 128;
      float p = 0.f;
#pragma unroll
      for (int k = 0; k < 128; k += 8) {
        short8 wv = *(const short8*)(wr + k);
#pragma unroll
        for (int e = 0; e < 8; ++e) p += b2f((u16)wv[e]) * hl[k + e];
      }
      pout[((long)b * 8 + kc) * 3328 + r] = p;
    }
  }
}

// ---------------- pipelined per-step kernel ----------------
// grid 256 = (b = blk>>3, jc = blk&7), 512 threads.
// pin  = k-partial gate sums for step t   (sum over kc gives Wcat.h_t)
// pout = k-partial gate sums for step t+1 (this block contributes its jc k-slice)
// Phases (all intra-block):
//  1: uh = tanh(sum_kc pin + U_b)         [redundant per jc, trivial]
//  2: scores + softmax                     [redundant per jc, 64KB bf16 wvf]
//  3: gm = attn . FWb[b, jc cols]          [98KB slice, no redundancy]
//  4+5: gh from pin + GRU combine -> h_{t+1}[b, jc cols], write h/Hbuf
//  6: pout[b][jc][r] = Wcat[r, jc-slice] . h_{t+1}[b, jc-slice]  (852KB col-slice,
//     shared by the 32 same-jc blocks on one XCD -> L2-resident)
__global__ __launch_bounds__(512)
void stepk(const u16* __restrict__ Wcat,   // (3328,1024) bf16
           const float* __restrict__ bcat, // (3328,)
           const u16* __restrict__ wvfb,   // (4096,256) bf16
           const u16* __restrict__ FWb,    // (4096,3072) bf16
           const float* __restrict__ GX,   // (1024,3072) f32, row t*32+b
           const float* __restrict__ pb,
           const float* __restrict__ pin,  // (32,8,3328) f32
           float* __restrict__ pout,       // (32,8,3328) f32
           float* __restrict__ h,          // (32,1024) f32
           u16* __restrict__ Hbuf,         // (1024,1024) bf16
           int t) {
  const int b = blockIdx.x >> 3, jc = blockIdx.x & 7;
  const int tid = threadIdx.x;

  __shared__ float uhl[256];
  __shared__ float part[512];
  __shared__ float attn[128];
  __shared__ float gmp[3][512];
  __shared__ float hl2[128];

  // Phase 1: uh (sum 8 k-partials + bias, tanh)
  if (tid < 256) {
    const float* pp = pin + ((long)b * 8) * 3328 + tid;
    float s = 0.f;
#pragma unroll
    for (int kc = 0; kc < 8; ++kc) s += pp[kc * 3328];
    uhl[tid] = tanhf(s + bcat[tid]);
  }
  __syncthreads();

  // Phase 2: scores. s = tid&127, q = tid>>7 covers 64 of 256 dims.
  {
    const int s = tid & 127, q = tid >> 7;
    const u16* wr = wvfb + ((long)(b * 128 + s)) * 256 + q * 64;
    const float* uq = &uhl[q * 64];
    float p = 0.f;
#pragma unroll
    for (int d = 0; d < 64; d += 8) {
      short8 wv = *(const short8*)(wr + d);
#pragma unroll
      for (int e = 0; e < 8; ++e) p += b2f((u16)wv[e]) * uq[d + e];
    }
    part[tid] = p;
  }
  __syncthreads();
  if (tid < 128)
    attn[tid] = part[tid] + part[tid + 128] + part[tid + 256] + part[tid + 384] + pb[0];
  __syncthreads();
  if (tid < 64) {
    float m = fmaxf(attn[tid], attn[tid + 64]);
#pragma unroll
    for (int o = 32; o; o >>= 1) m = fmaxf(m, __shfl_xor(m, o));
    float e0 = expf(attn[tid] - m), e1 = expf(attn[tid + 64] - m);
    float s2 = e0 + e1;
#pragma unroll
    for (int o = 32; o; o >>= 1) s2 += __shfl_xor(s2, o);
    float inv = 1.f / s2;
    attn[tid] = e0 * inv;
    attn[tid + 64] = e1 * inv;
  }
  __syncthreads();

  // Phase 3: gm partials. ml = tid&127 -> col, sh = tid>>7 -> 32 s-positions.
  {
    const int ml = tid & 127, sh = tid >> 7;
    const int col = jc * 128 + ml;
    float g0 = 0.f, g1 = 0.f, g2 = 0.f;
    const u16* fw = FWb + ((long)(b * 128 + sh * 32)) * 3072 + col;
#pragma unroll 4
    for (int s = 0; s < 32; ++s) {
      float a = attn[sh * 32 + s];
      g0 += a * b2f(fw[0]);
      g1 += a * b2f(fw[1024]);
      g2 += a * b2f(fw[2048]);
      fw += 3072;
    }
    gmp[0][tid] = g0; gmp[1][tid] = g1; gmp[2][tid] = g2;
  }
  __syncthreads();

  // Phase 4+5: gh from k-partials + GRU combine for cols jc*128..+127
  if (tid < 128) {
    const int m = jc * 128 + tid;
    float gm0 = gmp[0][tid] + gmp[0][tid + 128] + gmp[0][tid + 256] + gmp[0][tid + 384];
    float gm1 = gmp[1][tid] + gmp[1][tid + 128] + gmp[1][tid + 256] + gmp[1][tid + 384];
    float gm2 = gmp[2][tid] + gmp[2][tid + 128] + gmp[2][tid + 256] + gmp[2][tid + 384];
    float gh0 = 0.f, gh1 = 0.f, gh2 = 0.f;
    const float* pp = pin + ((long)b * 8) * 3328 + 256 + m;
#pragma unroll
    for (int kc = 0; kc < 8; ++kc) {
      const float* pk = pp + kc * 3328;
      gh0 += pk[0];
      gh1 += pk[1024];
      gh2 += pk[2048];
    }
    gh0 += bcat[256 + m];
    gh1 += bcat[1280 + m];
    gh2 += bcat[2304 + m];
    const long gxo = ((long)t * 32 + b) * 3072;
    float xr = GX[gxo + m] + gm0;
    float xz = GX[gxo + 1024 + m] + gm1;
    float xn = GX[gxo + 2048 + m] + gm2;
    float r = 1.f / (1.f + expf(-(xr + gh0)));
    float z = 1.f / (1.f + expf(-(xz + gh1)));
    float n = tanhf(xn + r * gh2);
    float hv = h[b * 1024 + m];
    float h2 = (1.f - z) * n + z * hv;
    h[b * 1024 + m] = h2;
    hl2[tid] = h2;
    Hbuf[((long)t * 32 + b) * 1024 + m] = f2b(h2);
  }
  __syncthreads();

  // Phase 6: k-partial gates for step t+1 over this block's jc k-slice.
  {
    const int c0 = jc * 128;
    for (int j = 0; j < 7; ++j) {
      int r = j * 512 + tid;
      if (r < 3328) {
        const u16* wr = Wcat + (long)r * 1024 + c0;
        float p = 0.f;
#pragma unroll
        for (int k = 0; k < 128; k += 8) {
          short8 wv = *(const short8*)(wr + k);
#pragma unroll
          for (int e = 0; e < 8; ++e) p += b2f((u16)wv[e]) * hl2[k + e];
        }
        pout[((long)b * 8 + jc) * 3328 + r] = p;
      }
    }
  }
}

// ---------------- launcher ----------------

extern "C" void kernel_launch(void* const* d_in, const int* in_sizes, int n_in,
                              void* d_out, int out_size, void* d_ws, size_t ws_size,
                              hipStream_t stream) {
  const float* f    = (const float*)d_in[0];
  const float* h0   = (const float*)d_in[1];
  const float* gt   = (const float*)d_in[2];
  const float* U_w  = (const float*)d_in[4];
  const float* U_b  = (const float*)d_in[5];
  const float* V_w  = (const float*)d_in[6];
  const float* V_b  = (const float*)d_in[7];
  const float* P_w  = (const float*)d_in[8];
  const float* P_b  = (const float*)d_in[9];
  const float* W_ih = (const float*)d_in[10];
  const float* b_ih = (const float*)d_in[11];
  const float* W_hh = (const float*)d_in[12];
  const float* b_hh = (const float*)d_in[13];
  const float* dw   = (const float*)d_in[14];
  const float* db   = (const float*)d_in[15];

  char* w = (char*)d_ws;
  auto alloc = [&](size_t bytes) { char* p = w; w += (bytes + 255) & ~255ULL; return p; };

  u16*   fbf   = (u16*)alloc(4096L * 1024 * 2);
  u16*   VwBf  = (u16*)alloc(256L * 1024 * 2);
  u16*   Wcat  = (u16*)alloc(3328L * 1024 * 2);   // bf16 [U_w; W_hh]
  u16*   WxBf  = (u16*)alloc(3072L * 512 * 2);
  u16*   WmBf  = (u16*)alloc(3072L * 1024 * 2);
  u16*   dwBf  = (u16*)alloc(32000L * 1024 * 2);
  u16*   Xbf   = (u16*)alloc(1024L * 512 * 2);
  u16*   wvfb  = (u16*)alloc(4096L * 256 * 2);    // bf16 wvf
  float* GX    = (float*)alloc(1024L * 3072 * 4);
  u16*   FWb   = (u16*)alloc(4096L * 3072 * 2);
  float* hf32  = (float*)alloc(32L * 1024 * 4);
  float* p0    = (float*)alloc(32L * 8 * 3328 * 4);
  float* p1    = (float*)alloc(32L * 8 * 3328 * 4);
  u16*   Hbuf  = (u16*)alloc(1024L * 1024 * 2);
  float* bcat  = (float*)alloc(3328L * 4);

  auto cvg = [](long n) { long g = (n + 1023) / 1024; return (int)(g > 2048 ? 2048 : g); };

  cvt_flat<<<cvg(4194304), 256, 0, stream>>>(f, fbf, 4194304);
  cvt_flat<<<cvg(262144), 256, 0, stream>>>(V_w, VwBf, 262144);
  cvt_flat<<<cvg(262144), 256, 0, stream>>>(U_w, Wcat, 262144);
  cvt_flat<<<cvg(3145728), 256, 0, stream>>>(W_hh, Wcat + 262144L, 3145728);
  cvt_strided<<<2048, 256, 0, stream>>>(W_ih, WxBf, 3072L * 512, 9, 1536, 0);
  cvt_strided<<<2048, 256, 0, stream>>>(W_ih, WmBf, 3072L * 1024, 10, 1536, 512);
  cvt_flat<<<cvg(32768000), 256, 0, stream>>>(dw, dwBf, 32768000);
  cvt_x<<<2048, 256, 0, stream>>>(gt, Xbf);
  hipMemcpyAsync(hf32, h0, 32L * 1024 * 4, hipMemcpyDeviceToDevice, stream);
  hipMemcpyAsync(bcat, U_b, 256 * 4, hipMemcpyDeviceToDevice, stream);
  hipMemcpyAsync(bcat + 256, b_hh, 3072 * 4, hipMemcpyDeviceToDevice, stream);

  // loop-invariant GEMMs
  gemm_bt<1><<<dim3(2, 32), 256, 0, stream>>>(fbf, VwBf, wvfb, V_b, P_w, 4096, 256, 1024);
  gemm_bt<2><<<dim3(24, 8), 256, 0, stream>>>(Xbf, WxBf, GX, b_ih, nullptr, 992, 3072, 512);
  gemm_bt<0><<<dim3(24, 32), 256, 0, stream>>>(fbf, WmBf, FWb, nullptr, nullptr, 4096, 3072, 1024);

  // t=0 gate partials from h0
  init_partial<<<256, 512, 0, stream>>>(Wcat, h0, p0);

  // recurrence: ONE kernel per step, gates pipelined via k-partials
  for (int t = 0; t < 31; ++t) {
    float* pin  = (t & 1) ? p1 : p0;
    float* pout = (t & 1) ? p0 : p1;
    stepk<<<256, 512, 0, stream>>>(Wcat, bcat, wvfb, FWb, GX, P_b, pin, pout, hf32, Hbuf, t);
  }

  // logits
  gemm_bt<3><<<dim3(250, 8), 256, 0, stream>>>(Hbuf, dwBf, (float*)d_out, db, nullptr,
                                               992, 32000, 1024);
}

// Round 6
// 1586.373 us; speedup vs baseline: 7.7990x; 1.3906x over previous
//
#include <hip/hip_runtime.h>
#include <hip/hip_bf16.h>
#include <math.h>

typedef unsigned short u16;
typedef unsigned long long u64;
typedef __attribute__((ext_vector_type(8))) short short8;
typedef __attribute__((ext_vector_type(4))) float f32x4;

static __device__ __forceinline__ u16 f2b(float x) {
  __hip_bfloat16 h = __float2bfloat16(x);
  return *reinterpret_cast<u16*>(&h);
}
static __device__ __forceinline__ float b2f(u16 u) {
  unsigned int v = ((unsigned int)u) << 16;
  float f;
  __builtin_memcpy(&f, &v, 4);
  return f;
}

// agent-scope relaxed (cache-bypassing) accessors — cross-XCD data passing
// WITHOUT any acquire/release fence (no L2 invalidation).
static __device__ __forceinline__ float aldf(const float* p) {
  return __hip_atomic_load(const_cast<float*>(p), __ATOMIC_RELAXED, __HIP_MEMORY_SCOPE_AGENT);
}
static __device__ __forceinline__ void astf(float* p, float v) {
  __hip_atomic_store(p, v, __ATOMIC_RELAXED, __HIP_MEMORY_SCOPE_AGENT);
}
static __device__ __forceinline__ u64 ald8(const u64* p) {
  return __hip_atomic_load(const_cast<u64*>(p), __ATOMIC_RELAXED, __HIP_MEMORY_SCOPE_AGENT);
}

// ---------------- conversion kernels ----------------

__global__ void cvt_flat(const float* __restrict__ s, u16* __restrict__ d, long n) {
  long i = ((long)blockIdx.x * 256 + threadIdx.x) * 4;
  long stride = (long)gridDim.x * 1024;
  for (; i < n; i += stride) {
    float4 v = *(const float4*)(s + i);
    ushort4 o;
    o.x = f2b(v.x); o.y = f2b(v.y); o.z = f2b(v.z); o.w = f2b(v.w);
    *(ushort4*)(d + i) = o;
  }
}

__global__ void cvt_strided(const float* __restrict__ s, u16* __restrict__ d,
                            long total, int lshift, long sstride, long soff) {
  long i = (long)blockIdx.x * 256 + threadIdx.x;
  long step = (long)gridDim.x * 256;
  long mask = (1L << lshift) - 1;
  for (; i < total; i += step) {
    long r = i >> lshift;
    long c = i & mask;
    d[i] = f2b(s[r * sstride + soff + c]);
  }
}

__global__ void cvt_x(const float* __restrict__ gt, u16* __restrict__ d) {
  long idx = (long)blockIdx.x * 256 + threadIdx.x;
  if (idx >= 1024L * 512) return;
  long m = idx >> 9;
  int k = (int)(idx & 511);
  if (m < 992) {
    int tt = (int)(m >> 5), b = (int)(m & 31);
    d[idx] = f2b(gt[((long)b * 32 + tt) * 512 + k]);
  } else {
    d[idx] = 0;
  }
}

// ---------------- generic MFMA GEMM: C = A(M,K) * B(N,K)^T ----------------
template<int EPI>
__global__ __launch_bounds__(256)
void gemm_bt(const u16* __restrict__ A, const u16* __restrict__ B,
             void* __restrict__ C0,
             const float* __restrict__ bias, const float* __restrict__ pw,
             int M, int N, int K) {
  __shared__ u16 As[4096];
  __shared__ u16 Bs[4096];
  const int tid = threadIdx.x;
  const int lane = tid & 63, wid = tid >> 6;

  int gx = gridDim.x, gy = gridDim.y;
  int orig = blockIdx.y * gx + blockIdx.x;
  int G = gx < 8 ? gx : 8;
  int ng = gx / G;
  int full = ng * G * gy;
  int ct, rt;
  if (orig < full) {
    int grp = orig / (G * gy), rem = orig % (G * gy);
    ct = grp * G + rem % G;
    rt = rem / G;
  } else {
    int Gt = gx - ng * G;
    int rem = orig - full;
    ct = ng * G + rem % Gt;
    rt = rem / Gt;
  }
  const long row0 = (long)rt * 128;
  const long col0 = (long)ct * 128;

  const int wm = (wid >> 1) * 64, wn = (wid & 1) * 64;
  const int fr = lane & 15, fq = lane >> 4;
  const int sr = wid * 16 + (lane >> 2);
  const int sc = (lane & 3) * 8;

  const u16* Ag0 = A + (row0 + sr) * (long)K + sc;
  const u16* Ag1 = Ag0 + 64 * (long)K;
  const u16* Bg0 = B + (col0 + sr) * (long)K + sc;
  const u16* Bg1 = Bg0 + 64 * (long)K;

  u16* AsW0 = &As[wid * 512];
  u16* AsW1 = &As[2048 + wid * 512];
  u16* BsW0 = &Bs[wid * 512];
  u16* BsW1 = &Bs[2048 + wid * 512];

  f32x4 acc[4][4];
#pragma unroll
  for (int i = 0; i < 4; ++i)
#pragma unroll
    for (int j = 0; j < 4; ++j) acc[i][j] = {0.f, 0.f, 0.f, 0.f};

  for (int k0 = 0; k0 < K; k0 += 32) {
    __builtin_amdgcn_global_load_lds((const __attribute__((address_space(1))) void*)(Ag0 + k0),
                                     (__attribute__((address_space(3))) void*)AsW0, 16, 0, 0);
    __builtin_amdgcn_global_load_lds((const __attribute__((address_space(1))) void*)(Ag1 + k0),
                                     (__attribute__((address_space(3))) void*)AsW1, 16, 0, 0);
    __builtin_amdgcn_global_load_lds((const __attribute__((address_space(1))) void*)(Bg0 + k0),
                                     (__attribute__((address_space(3))) void*)BsW0, 16, 0, 0);
    __builtin_amdgcn_global_load_lds((const __attribute__((address_space(1))) void*)(Bg1 + k0),
                                     (__attribute__((address_space(3))) void*)BsW1, 16, 0, 0);
    __syncthreads();
    short8 af[4], bfv[4];
#pragma unroll
    for (int i = 0; i < 4; ++i) af[i] = *(const short8*)&As[(wm + i * 16 + fr) * 32 + fq * 8];
#pragma unroll
    for (int i = 0; i < 4; ++i) bfv[i] = *(const short8*)&Bs[(wn + i * 16 + fr) * 32 + fq * 8];
#pragma unroll
    for (int i = 0; i < 4; ++i)
#pragma unroll
      for (int j = 0; j < 4; ++j)
        acc[i][j] = __builtin_amdgcn_mfma_f32_16x16x32_bf16(af[i], bfv[j], acc[i][j], 0, 0, 0);
    __syncthreads();
  }

#pragma unroll
  for (int i = 0; i < 4; ++i)
#pragma unroll
    for (int j = 0; j < 4; ++j)
#pragma unroll
      for (int q = 0; q < 4; ++q) {
        long gr = row0 + wm + i * 16 + fq * 4 + q;
        long gc = col0 + wn + j * 16 + fr;
        float v = acc[i][j][q];
        if constexpr (EPI == 0) {
          ((u16*)C0)[gr * (long)N + gc] = f2b(v);
        } else if constexpr (EPI == 1) {
          ((u16*)C0)[gr * (long)N + gc] = f2b(tanhf(v + bias[gc]) * pw[gc]);
        } else if constexpr (EPI == 2) {
          if (gr < M) ((float*)C0)[gr * (long)N + gc] = v + bias[gc];
        } else {  // EPI == 3
          if (gr < M) {
            long bb = gr & 31, tt = gr >> 5;
            float o = v + bias[gc];
            __builtin_nontemporal_store(o, &((float*)C0)[(bb * 31 + tt) * (long)N + gc]);
          }
        }
      }
}

// ---------------- persistent recurrence kernel ----------------
// 256 blocks x 512 threads, cooperative (co-residency guarantee only).
// Custom barrier: relaxed agent atomicAdd + spin. NO acquire/release fences,
// so per-XCD L2s keep the (read-only) weights resident across all 31 steps.
// All cross-block data (hG, gates) moves via agent-scope relaxed atomics
// (cache-bypassing), ordered by the barrier handshake (__syncthreads drains
// vmcnt before s_barrier, so stores are at the coherence point before arrive).
//
// Per step:
//  phase A (gates GEMV, batched over b): block = (rowg = blk>>2, bg = blk&3).
//    Reads h[8 b's] coherent -> LDS; Wcat f32 rows [rowg*52,+52) plain (L2-hot);
//    writes raw gate dots to gates[b][r] coherent.
//  barrier
//  phase B (attention + GRU): block = (b = blk>>3, jc = blk&7).
//    uh = tanh(gates[b][0:256]+U_b); scores vs wvfb (plain, L2-hot); softmax;
//    gm over FWb jc-slice (plain, L2-hot); gh from gates (coherent) + b_hh;
//    GRU combine with h-slice kept in LDS across steps; write h coherent,
//    Hbuf plain.
//  barrier
__global__ __launch_bounds__(512)
void persist(const float* __restrict__ WcatF, const float* __restrict__ bcat,
             const u16* __restrict__ wvfb, const u16* __restrict__ FWb,
             const float* __restrict__ GX, const float* __restrict__ pbv,
             float* __restrict__ hG, float* __restrict__ gates,
             u16* __restrict__ Hbuf, unsigned* __restrict__ cnt) {
  const int tid = threadIdx.x;
  const int blk = blockIdx.x;
  const int rowg = blk >> 2, bg = blk & 3;  // phase A role
  const int b = blk >> 3, jc = blk & 7;     // phase B role

  __shared__ float hA[8][1032];   // padded stride: bank-conflict-free
  __shared__ float uhl[256];
  __shared__ float part[512];
  __shared__ float attnv[128];
  __shared__ float gmp[3][512];
  __shared__ float hl2[128];      // this block's persistent h slice

  const float pb0 = pbv[0];

  if (tid < 128) hl2[tid] = hG[(long)b * 1024 + jc * 128 + tid];

  auto xbar = [&](unsigned target) {
    __syncthreads();  // drains vmcnt(0): all this block's stores are visible
    if (tid == 0) {
      __hip_atomic_fetch_add(cnt, 1u, __ATOMIC_RELAXED, __HIP_MEMORY_SCOPE_AGENT);
      while (__hip_atomic_load(cnt, __ATOMIC_RELAXED, __HIP_MEMORY_SCOPE_AGENT) < target) {
        __builtin_amdgcn_s_sleep(2);
      }
    }
    __syncthreads();
  };

  for (int t = 0; t < 31; ++t) {
    // ---------------- phase A: gate dots, batched over 8 b ----------------
    for (int i = tid; i < 4096; i += 512) {
      int bi = i >> 9, off = (i & 511) << 1;
      u64 v = ald8((const u64*)(hG + (long)(bg * 8 + bi) * 1024 + off));
      float2 f2v;
      __builtin_memcpy(&f2v, &v, 8);
      hA[bi][off] = f2v.x;
      hA[bi][off + 1] = f2v.y;
    }
    __syncthreads();
    if (tid < 416) {
      const int bi = tid & 7, ri = tid >> 3;
      const int r = rowg * 52 + ri;
      const float* wr = WcatF + (long)r * 1024;
      const float* hh = hA[bi];
      float acc = 0.f;
#pragma unroll 8
      for (int k = 0; k < 1024; k += 4) {
        float4 wv = *(const float4*)(wr + k);
        float4 hv = *(const float4*)(hh + k);
        acc += wv.x * hv.x + wv.y * hv.y + wv.z * hv.z + wv.w * hv.w;
      }
      astf(gates + (long)(bg * 8 + bi) * 3328 + r, acc);
    }
    xbar(256u * (2 * t + 1));

    // ---------------- phase B: attention + GRU ----------------
    if (tid < 128) {
      u64 v = ald8((const u64*)(gates + (long)b * 3328 + tid * 2));
      float2 f2v;
      __builtin_memcpy(&f2v, &v, 8);
      uhl[tid * 2] = tanhf(f2v.x + bcat[tid * 2]);
      uhl[tid * 2 + 1] = tanhf(f2v.y + bcat[tid * 2 + 1]);
    }
    __syncthreads();
    {
      const int s = tid & 127, q = tid >> 7;
      const u16* wr = wvfb + ((long)(b * 128 + s)) * 256 + q * 64;
      const float* uq = &uhl[q * 64];
      float p = 0.f;
#pragma unroll
      for (int d = 0; d < 64; d += 8) {
        short8 wv = *(const short8*)(wr + d);
#pragma unroll
        for (int e = 0; e < 8; ++e) p += b2f((u16)wv[e]) * uq[d + e];
      }
      part[tid] = p;
    }
    __syncthreads();
    if (tid < 128)
      attnv[tid] = part[tid] + part[tid + 128] + part[tid + 256] + part[tid + 384] + pb0;
    __syncthreads();
    if (tid < 64) {
      float m = fmaxf(attnv[tid], attnv[tid + 64]);
#pragma unroll
      for (int o = 32; o; o >>= 1) m = fmaxf(m, __shfl_xor(m, o));
      float e0 = expf(attnv[tid] - m), e1 = expf(attnv[tid + 64] - m);
      float s2 = e0 + e1;
#pragma unroll
      for (int o = 32; o; o >>= 1) s2 += __shfl_xor(s2, o);
      float inv = 1.f / s2;
      attnv[tid] = e0 * inv;
      attnv[tid + 64] = e1 * inv;
    }
    __syncthreads();
    {
      const int ml = tid & 127, sh = tid >> 7;
      const int col = jc * 128 + ml;
      float g0 = 0.f, g1 = 0.f, g2 = 0.f;
      const u16* fw = FWb + ((long)(b * 128 + sh * 32)) * 3072 + col;
#pragma unroll 4
      for (int s = 0; s < 32; ++s) {
        float a = attnv[sh * 32 + s];
        g0 += a * b2f(fw[0]);
        g1 += a * b2f(fw[1024]);
        g2 += a * b2f(fw[2048]);
        fw += 3072;
      }
      gmp[0][tid] = g0; gmp[1][tid] = g1; gmp[2][tid] = g2;
    }
    __syncthreads();
    if (tid < 128) {
      const int m = jc * 128 + tid;
      float gm0 = gmp[0][tid] + gmp[0][tid + 128] + gmp[0][tid + 256] + gmp[0][tid + 384];
      float gm1 = gmp[1][tid] + gmp[1][tid + 128] + gmp[1][tid + 256] + gmp[1][tid + 384];
      float gm2 = gmp[2][tid] + gmp[2][tid + 128] + gmp[2][tid + 256] + gmp[2][tid + 384];
      float gh0 = aldf(gates + (long)b * 3328 + 256 + m) + bcat[256 + m];
      float gh1 = aldf(gates + (long)b * 3328 + 1280 + m) + bcat[1280 + m];
      float gh2 = aldf(gates + (long)b * 3328 + 2304 + m) + bcat[2304 + m];
      const long gxo = ((long)t * 32 + b) * 3072;
      float xr = GX[gxo + m] + gm0;
      float xz = GX[gxo + 1024 + m] + gm1;
      float xn = GX[gxo + 2048 + m] + gm2;
      float r = 1.f / (1.f + expf(-(xr + gh0)));
      float z = 1.f / (1.f + expf(-(xz + gh1)));
      float n = tanhf(xn + r * gh2);
      float h2 = (1.f - z) * n + z * hl2[tid];
      hl2[tid] = h2;
      astf(hG + (long)b * 1024 + m, h2);
      Hbuf[((long)t * 32 + b) * 1024 + m] = f2b(h2);
    }
    xbar(256u * (2 * t + 2));
  }
}

// ---------------- launcher ----------------

extern "C" void kernel_launch(void* const* d_in, const int* in_sizes, int n_in,
                              void* d_out, int out_size, void* d_ws, size_t ws_size,
                              hipStream_t stream) {
  const float* f    = (const float*)d_in[0];
  const float* h0   = (const float*)d_in[1];
  const float* gt   = (const float*)d_in[2];
  const float* U_w  = (const float*)d_in[4];
  const float* U_b  = (const float*)d_in[5];
  const float* V_w  = (const float*)d_in[6];
  const float* V_b  = (const float*)d_in[7];
  const float* P_w  = (const float*)d_in[8];
  const float* P_b  = (const float*)d_in[9];
  const float* W_ih = (const float*)d_in[10];
  const float* b_ih = (const float*)d_in[11];
  const float* W_hh = (const float*)d_in[12];
  const float* b_hh = (const float*)d_in[13];
  const float* dw   = (const float*)d_in[14];
  const float* db   = (const float*)d_in[15];

  char* w = (char*)d_ws;
  auto alloc = [&](size_t bytes) { char* p = w; w += (bytes + 255) & ~255ULL; return p; };

  u16*   fbf   = (u16*)alloc(4096L * 1024 * 2);
  u16*   VwBf  = (u16*)alloc(256L * 1024 * 2);
  float* WcatF = (float*)alloc(3328L * 1024 * 4);  // f32 [U_w; W_hh]
  u16*   WxBf  = (u16*)alloc(3072L * 512 * 2);
  u16*   WmBf  = (u16*)alloc(3072L * 1024 * 2);
  u16*   dwBf  = (u16*)alloc(32000L * 1024 * 2);
  u16*   Xbf   = (u16*)alloc(1024L * 512 * 2);
  u16*   wvfb  = (u16*)alloc(4096L * 256 * 2);
  float* GX    = (float*)alloc(1024L * 3072 * 4);
  u16*   FWb   = (u16*)alloc(4096L * 3072 * 2);
  float* hG    = (float*)alloc(32L * 1024 * 4);
  float* gates = (float*)alloc(32L * 3328 * 4);
  u16*   Hbuf  = (u16*)alloc(1024L * 1024 * 2);
  float* bcat  = (float*)alloc(3328L * 4);
  unsigned* cnt = (unsigned*)alloc(256);

  auto cvg = [](long n) { long g = (n + 1023) / 1024; return (int)(g > 2048 ? 2048 : g); };

  cvt_flat<<<cvg(4194304), 256, 0, stream>>>(f, fbf, 4194304);
  cvt_flat<<<cvg(262144), 256, 0, stream>>>(V_w, VwBf, 262144);
  cvt_strided<<<2048, 256, 0, stream>>>(W_ih, WxBf, 3072L * 512, 9, 1536, 0);
  cvt_strided<<<2048, 256, 0, stream>>>(W_ih, WmBf, 3072L * 1024, 10, 1536, 512);
  cvt_flat<<<cvg(32768000), 256, 0, stream>>>(dw, dwBf, 32768000);
  cvt_x<<<2048, 256, 0, stream>>>(gt, Xbf);
  hipMemcpyAsync(WcatF, U_w, 256L * 1024 * 4, hipMemcpyDeviceToDevice, stream);
  hipMemcpyAsync(WcatF + 262144, W_hh, 3072L * 1024 * 4, hipMemcpyDeviceToDevice, stream);
  hipMemcpyAsync(hG, h0, 32L * 1024 * 4, hipMemcpyDeviceToDevice, stream);
  hipMemcpyAsync(bcat, U_b, 256 * 4, hipMemcpyDeviceToDevice, stream);
  hipMemcpyAsync(bcat + 256, b_hh, 3072 * 4, hipMemcpyDeviceToDevice, stream);
  hipMemsetAsync(cnt, 0, 4, stream);

  // loop-invariant GEMMs
  gemm_bt<1><<<dim3(2, 32), 256, 0, stream>>>(fbf, VwBf, wvfb, V_b, P_w, 4096, 256, 1024);
  gemm_bt<2><<<dim3(24, 8), 256, 0, stream>>>(Xbf, WxBf, GX, b_ih, nullptr, 992, 3072, 512);
  gemm_bt<0><<<dim3(24, 32), 256, 0, stream>>>(fbf, WmBf, FWb, nullptr, nullptr, 4096, 3072, 1024);

  // full recurrence: one persistent kernel, custom non-invalidating barrier
  {
    void* ka[] = {(void*)&WcatF, (void*)&bcat, (void*)&wvfb, (void*)&FWb,
                  (void*)&GX,    (void*)&P_b,  (void*)&hG,   (void*)&gates,
                  (void*)&Hbuf,  (void*)&cnt};
    hipLaunchCooperativeKernel((void*)persist, dim3(256), dim3(512), ka, 0, stream);
  }

  // logits
  gemm_bt<3><<<dim3(250, 8), 256, 0, stream>>>(Hbuf, dwBf, (float*)d_out, db, nullptr,
                                               992, 32000, 1024);
}